// Round 10
// baseline (754.252 us; speedup 1.0000x reference)
//
#include <hip/hip_runtime.h>
#include <hip/hip_bf16.h>
#include <math.h>

#define HW    16384
#define Bsz   4
#define CIN   32
#define COUT  64
#define RED   16
#define KKN   49
#define GG    4
#define PW    134           // padded width/height (128 + 2*3)
#define PPLANE (PW*PW)

typedef __hip_bfloat16 bf16;

__device__ __forceinline__ float gelu_f(float x) {
    return 0.5f * x * (1.0f + erff(x * 0.70710678118654752f));
}
__device__ __forceinline__ void unpack_bf2(unsigned u, float& lo, float& hi) {
    lo = __uint_as_float(u << 16);
    hi = __uint_as_float(u & 0xffff0000u);
}
__device__ __forceinline__ unsigned pack_bf2(float lo, float hi) {
    unsigned a = __float_as_uint(lo), b = __float_as_uint(hi);
    a += 0x7fff + ((a >> 16) & 1);
    b += 0x7fff + ((b >> 16) & 1);
    return (a >> 16) | (b & 0xffff0000u);
}

// ---- workspace layout (bytes) ----
#define OFF_RBUF  9437184
#define OFF_X2B   13631488
#define OFF_PAR   22020096
#define PW1T 0
#define PWRT 2048
#define PW2T (2048+1024)
#define PWMT (2048+1024+4096)
#define PRSH (2048+1024+4096+2048)
#define PSHC (PRSH+16)
#define PSMV (PSHC+64)
#define PSC1 (PSMV+64)
#define PSH1 (PSC1+64)

__global__ __launch_bounds__(256) void k0_zero(uint4* __restrict__ x1pad, int n16) {
    int i = blockIdx.x * 256 + threadIdx.x;
    if (i < n16) x1pad[i] = make_uint4(0u, 0u, 0u, 0u);
}

__global__ __launch_bounds__(256) void k0_prep(
    const float* __restrict__ w1, const float* __restrict__ wr,
    const float* __restrict__ gr, const float* __restrict__ br,
    const float* __restrict__ mr, const float* __restrict__ vr,
    const float* __restrict__ g1, const float* __restrict__ b1,
    const float* __restrict__ m1, const float* __restrict__ v1,
    const float* __restrict__ w2, const float* __restrict__ g2,
    const float* __restrict__ b2, const float* __restrict__ m2,
    const float* __restrict__ v2,
    const float* __restrict__ wm, const float* __restrict__ bmap,
    const float* __restrict__ gm, const float* __restrict__ betam,
    const float* __restrict__ mm, const float* __restrict__ vm,
    float* __restrict__ par)
{
    int t = threadIdx.x;
    for (int i = t; i < 2048; i += 256) {
        int c = i >> 6, o = i & 63;
        par[PW1T + i] = w1[o * CIN + c];
    }
    for (int i = t; i < 1024; i += 256) {
        int c = i >> 4, j = i & 15;
        float sc = gr[j] * rsqrtf(vr[j] + 1e-5f);
        par[PWRT + i] = wr[j * COUT + c] * sc;
    }
    for (int i = t; i < 4096; i += 256) {
        int c = i >> 6, o = i & 63;
        float s2 = g2[o] * rsqrtf(v2[o] + 1e-5f);
        float sm = gm[o] * rsqrtf(vm[o] + 1e-5f);
        par[PW2T + i] = w2[o * COUT + c] * (s2 / sm);
    }
    for (int i = t; i < 2048; i += 256) {
        int c = i >> 6, o = i & 63;
        par[PWMT + i] = wm[o * CIN + c];
    }
    if (t < 16) {
        float sc = gr[t] * rsqrtf(vr[t] + 1e-5f);
        par[PRSH + t] = br[t] - mr[t] * sc;
    }
    if (t < 64) {
        float s2 = g2[t] * rsqrtf(v2[t] + 1e-5f);
        float sm = gm[t] * rsqrtf(vm[t] + 1e-5f);
        par[PSHC + t] = (b2[t] - m2[t] * s2) + (betam[t] + (bmap[t] - mm[t]) * sm);
        par[PSMV + t] = sm;
        float s1 = g1[t] * rsqrtf(v1[t] + 1e-5f);
        par[PSC1 + t] = s1;
        par[PSH1 + t] = b1[t] - m1[t] * s1;
    }
}

__global__ __launch_bounds__(256, 4) void k1_conv1_gelu_reduce(
    const float* __restrict__ x, const float* __restrict__ par,
    unsigned* __restrict__ x1pad, float* __restrict__ rbuf)
{
    __shared__ float g_lds[COUT][65];

    int lane  = threadIdx.x & 63;
    int chunk = __builtin_amdgcn_readfirstlane(threadIdx.x >> 6);  // == group
    int b     = blockIdx.x >> 8;
    int p     = ((blockIdx.x & 255) << 6) + lane;
    int h = p >> 7, w = p & 127;

    float acc[16];
#pragma unroll
    for (int o = 0; o < 16; ++o) acc[o] = 0.f;
#pragma unroll 8
    for (int c = 0; c < CIN; ++c) {
        float xc = x[(b * CIN + c) * HW + p];
        const float* wrow = par + PW1T + c * 64 + chunk * 16;
#pragma unroll
        for (int o = 0; o < 16; ++o) acc[o] += xc * wrow[o];
    }

    unsigned pk[8];
#pragma unroll
    for (int o = 0; o < 16; ++o) {
        acc[o] = gelu_f(acc[o]);
        g_lds[chunk * 16 + o][lane] = acc[o];
    }
#pragma unroll
    for (int d = 0; d < 8; ++d) pk[d] = pack_bf2(acc[2 * d], acc[2 * d + 1]);
    unsigned* xo = x1pad + ((size_t)((b * GG + chunk) * PW + (h + 3)) * PW + (w + 3)) * 8;
    *(uint4*)xo       = make_uint4(pk[0], pk[1], pk[2], pk[3]);
    *(uint4*)(xo + 4) = make_uint4(pk[4], pk[5], pk[6], pk[7]);

    __syncthreads();

    float ra[4] = {0.f, 0.f, 0.f, 0.f};
#pragma unroll 8
    for (int c = 0; c < COUT; ++c) {
        float gv = g_lds[c][lane];
        const float* wrow = par + PWRT + c * 16 + chunk * 4;
#pragma unroll
        for (int jj = 0; jj < 4; ++jj) ra[jj] += gv * wrow[jj];
    }
    float t[4];
#pragma unroll
    for (int jj = 0; jj < 4; ++jj)
        t[jj] = fmaxf(ra[jj] + par[PRSH + chunk * 4 + jj], 0.f);
    *(float4*)&rbuf[((size_t)b * HW + p) * 16 + chunk * 4] =
        make_float4(t[0], t[1], t[2], t[3]);
}

// K23: per (b,g) block of 256 px. wk generated ROW-BY-ROW (wkr[7] only —
// no wk[49] array, live set ~50 VGPR, spill-proof; round 9's wk[49] +
// branch-free taps made the allocator spill 400 MB of scratch/dispatch).
__global__ __launch_bounds__(256, 4) void k23_involution(
    const unsigned* __restrict__ x1pad, const float* __restrict__ rbuf,
    const float* __restrict__ wsp, const float* __restrict__ bsp,
    const float* __restrict__ par, unsigned* __restrict__ x2b)
{
    int bg = blockIdx.x >> 6;
    int g = bg & 3, b = bg >> 2;
    int p = ((blockIdx.x & 63) << 8) + threadIdx.x;
    int h = p >> 7, w0 = p & 127;

    float r[RED];
    {
        const float4* rp = (const float4*)&rbuf[((size_t)b * HW + p) * 16];
        float4 r0 = rp[0], r1 = rp[1], r2 = rp[2], r3 = rp[3];
        r[0]=r0.x; r[1]=r0.y; r[2]=r0.z; r[3]=r0.w;
        r[4]=r1.x; r[5]=r1.y; r[6]=r1.z; r[7]=r1.w;
        r[8]=r2.x; r[9]=r2.y; r[10]=r2.z; r[11]=r2.w;
        r[12]=r3.x; r[13]=r3.y; r[14]=r3.z; r[15]=r3.w;
    }

    const float* wrow = wsp + g * KKN * RED;
    const float* brow = bsp + g * KKN;
    const unsigned* base = x1pad + ((size_t)(bg * PW + h) * PW + w0) * 8;

    float acc[RED];
#pragma unroll
    for (int c = 0; c < RED; ++c) acc[c] = 0.f;

#pragma unroll
    for (int i = 0; i < 7; ++i) {
        // generate the 7 dynamic weights of this tap row (uses r[], s_load ws)
        float wkr[7];
#pragma unroll
        for (int j = 0; j < 7; ++j) {
            int k = i * 7 + j;
            float s = brow[k];
#pragma unroll
            for (int jj = 0; jj < RED; ++jj) s += r[jj] * wrow[k * RED + jj];
            wkr[j] = s;
        }
        // apply them (unconditional — zero halo)
#pragma unroll
        for (int j = 0; j < 7; ++j) {
            float wv = wkr[j];
            const unsigned* tp = base + (size_t)(i * PW + j) * 8;
            uint4 A = *(const uint4*)tp;
            uint4 B = *(const uint4*)(tp + 4);
            float lo, hi;
            unpack_bf2(A.x, lo, hi); acc[0] += wv*lo; acc[1] += wv*hi;
            unpack_bf2(A.y, lo, hi); acc[2] += wv*lo; acc[3] += wv*hi;
            unpack_bf2(A.z, lo, hi); acc[4] += wv*lo; acc[5] += wv*hi;
            unpack_bf2(A.w, lo, hi); acc[6] += wv*lo; acc[7] += wv*hi;
            unpack_bf2(B.x, lo, hi); acc[8] += wv*lo; acc[9] += wv*hi;
            unpack_bf2(B.y, lo, hi); acc[10]+= wv*lo; acc[11]+= wv*hi;
            unpack_bf2(B.z, lo, hi); acc[12]+= wv*lo; acc[13]+= wv*hi;
            unpack_bf2(B.w, lo, hi); acc[14]+= wv*lo; acc[15]+= wv*hi;
        }
    }

    unsigned pk[8];
#pragma unroll
    for (int d = 0; d < 8; ++d) {
        int ch0 = g * RED + 2 * d, ch1 = ch0 + 1;
        float v0 = gelu_f(par[PSC1 + ch0] * acc[2 * d]     + par[PSH1 + ch0]);
        float v1 = gelu_f(par[PSC1 + ch1] * acc[2 * d + 1] + par[PSH1 + ch1]);
        pk[d] = pack_bf2(v0, v1);
    }
    unsigned* xo = x2b + ((size_t)bg * HW + p) * 8;
    *(uint4*)xo       = make_uint4(pk[0], pk[1], pk[2], pk[3]);
    *(uint4*)(xo + 4) = make_uint4(pk[4], pk[5], pk[6], pk[7]);
}

__global__ __launch_bounds__(256, 4) void k4_final(
    const unsigned* __restrict__ x2b, const float* __restrict__ x,
    const float* __restrict__ par, float* __restrict__ out)
{
    int lane  = threadIdx.x & 63;
    int chunk = __builtin_amdgcn_readfirstlane(threadIdx.x >> 6);
    int b     = blockIdx.x >> 8;
    int p     = ((blockIdx.x & 255) << 6) + lane;

    float acc[16];
#pragma unroll
    for (int o = 0; o < 16; ++o) acc[o] = 0.f;

#pragma unroll
    for (int gg = 0; gg < GG; ++gg) {
        const unsigned* up = x2b + ((size_t)(b * GG + gg) * HW + p) * 8;
        uint4 A = *(const uint4*)up;
        uint4 B = *(const uint4*)(up + 4);
        unsigned ud[8] = {A.x, A.y, A.z, A.w, B.x, B.y, B.z, B.w};
#pragma unroll
        for (int d = 0; d < 8; ++d) {
            float lo, hi;
            unpack_bf2(ud[d], lo, hi);
            int c0 = gg * 16 + 2 * d;
            const float* wr0 = par + PW2T + c0 * 64 + chunk * 16;
            const float* wr1 = wr0 + 64;
#pragma unroll
            for (int o = 0; o < 16; ++o) acc[o] += lo * wr0[o];
#pragma unroll
            for (int o = 0; o < 16; ++o) acc[o] += hi * wr1[o];
        }
    }
#pragma unroll 8
    for (int c = 0; c < CIN; ++c) {
        float xc = x[(b * CIN + c) * HW + p];
        const float* wrow = par + PWMT + c * 64 + chunk * 16;
#pragma unroll
        for (int o = 0; o < 16; ++o) acc[o] += xc * wrow[o];
    }
#pragma unroll
    for (int o = 0; o < 16; ++o) {
        int O = chunk * 16 + o;
        out[(size_t)(b * COUT + O) * HW + p] =
            gelu_f(par[PSMV + O] * acc[o] + par[PSHC + O]);
    }
}

extern "C" void kernel_launch(void* const* d_in, const int* in_sizes, int n_in,
                              void* d_out, int out_size, void* d_ws, size_t ws_size,
                              hipStream_t stream) {
    const float* x    = (const float*)d_in[0];
    const float* w1   = (const float*)d_in[1];
    const float* wr   = (const float*)d_in[2];
    const float* gr   = (const float*)d_in[3];
    const float* br   = (const float*)d_in[4];
    const float* mr   = (const float*)d_in[5];
    const float* vr   = (const float*)d_in[6];
    const float* wsp  = (const float*)d_in[7];
    const float* bsp  = (const float*)d_in[8];
    const float* g1   = (const float*)d_in[9];
    const float* b1   = (const float*)d_in[10];
    const float* m1   = (const float*)d_in[11];
    const float* v1   = (const float*)d_in[12];
    const float* w2   = (const float*)d_in[13];
    const float* g2   = (const float*)d_in[14];
    const float* b2   = (const float*)d_in[15];
    const float* m2   = (const float*)d_in[16];
    const float* v2   = (const float*)d_in[17];
    const float* wm   = (const float*)d_in[18];
    const float* bmap = (const float*)d_in[19];
    const float* gm   = (const float*)d_in[20];
    const float* betam= (const float*)d_in[21];
    const float* mm   = (const float*)d_in[22];
    const float* vm   = (const float*)d_in[23];

    unsigned* x1pad = (unsigned*)d_ws;
    float*    rbuf  = (float*)((char*)d_ws + OFF_RBUF);
    unsigned* x2b   = (unsigned*)((char*)d_ws + OFF_X2B);
    float*    par   = (float*)((char*)d_ws + OFF_PAR);

    int n16 = (16 * PPLANE * 32) / 16;
    k0_zero<<<(n16 + 255) / 256, 256, 0, stream>>>((uint4*)x1pad, n16);
    k0_prep<<<1, 256, 0, stream>>>(w1, wr, gr, br, mr, vr, g1, b1, m1, v1,
                                   w2, g2, b2, m2, v2, wm, bmap, gm, betam,
                                   mm, vm, par);
    k1_conv1_gelu_reduce<<<Bsz * HW / 64, 256, 0, stream>>>(x, par, x1pad, rbuf);
    k23_involution<<<Bsz * GG * HW / 256, 256, 0, stream>>>(
        x1pad, rbuf, wsp, bsp, par, x2b);
    k4_final<<<Bsz * HW / 64, 256, 0, stream>>>(x2b, x, par, (float*)d_out);
}

// Round 11
// 174.150 us; speedup vs baseline: 4.3311x; 4.3311x over previous
//
#include <hip/hip_runtime.h>
#include <hip/hip_bf16.h>
#include <math.h>

#define HW    16384
#define Bsz   4
#define CIN   32
#define COUT  64
#define RED   16
#define KKN   49
#define GG    4
#define PW    134           // padded width/height (128 + 2*3)
#define PPLANE (PW*PW)

typedef __hip_bfloat16 bf16;

__device__ __forceinline__ float gelu_f(float x) {
    return 0.5f * x * (1.0f + erff(x * 0.70710678118654752f));
}
__device__ __forceinline__ void unpack_bf2(unsigned u, float& lo, float& hi) {
    lo = __uint_as_float(u << 16);
    hi = __uint_as_float(u & 0xffff0000u);
}
__device__ __forceinline__ unsigned pack_bf2(float lo, float hi) {
    unsigned a = __float_as_uint(lo), b = __float_as_uint(hi);
    a += 0x7fff + ((a >> 16) & 1);
    b += 0x7fff + ((b >> 16) & 1);
    return (a >> 16) | (b & 0xffff0000u);
}

// ---- workspace layout (bytes) ----
#define OFF_RBUF  9437184
#define OFF_X2B   13631488
#define OFF_PAR   22020096
#define PW1T 0
#define PWRT 2048
#define PW2T (2048+1024)
#define PWMT (2048+1024+4096)
#define PRSH (2048+1024+4096+2048)
#define PSHC (PRSH+16)
#define PSMV (PSHC+64)
#define PSC1 (PSMV+64)
#define PSH1 (PSC1+64)

__global__ __launch_bounds__(256) void k0_zero(uint4* __restrict__ x1pad, int n16) {
    int i = blockIdx.x * 256 + threadIdx.x;
    if (i < n16) x1pad[i] = make_uint4(0u, 0u, 0u, 0u);
}

__global__ __launch_bounds__(256) void k0_prep(
    const float* __restrict__ w1, const float* __restrict__ wr,
    const float* __restrict__ gr, const float* __restrict__ br,
    const float* __restrict__ mr, const float* __restrict__ vr,
    const float* __restrict__ g1, const float* __restrict__ b1,
    const float* __restrict__ m1, const float* __restrict__ v1,
    const float* __restrict__ w2, const float* __restrict__ g2,
    const float* __restrict__ b2, const float* __restrict__ m2,
    const float* __restrict__ v2,
    const float* __restrict__ wm, const float* __restrict__ bmap,
    const float* __restrict__ gm, const float* __restrict__ betam,
    const float* __restrict__ mm, const float* __restrict__ vm,
    float* __restrict__ par)
{
    int t = threadIdx.x;
    for (int i = t; i < 2048; i += 256) {
        int c = i >> 6, o = i & 63;
        par[PW1T + i] = w1[o * CIN + c];
    }
    for (int i = t; i < 1024; i += 256) {
        int c = i >> 4, j = i & 15;
        float sc = gr[j] * rsqrtf(vr[j] + 1e-5f);
        par[PWRT + i] = wr[j * COUT + c] * sc;
    }
    for (int i = t; i < 4096; i += 256) {
        int c = i >> 6, o = i & 63;
        float s2 = g2[o] * rsqrtf(v2[o] + 1e-5f);
        float sm = gm[o] * rsqrtf(vm[o] + 1e-5f);
        par[PW2T + i] = w2[o * COUT + c] * (s2 / sm);
    }
    for (int i = t; i < 2048; i += 256) {
        int c = i >> 6, o = i & 63;
        par[PWMT + i] = wm[o * CIN + c];
    }
    if (t < 16) {
        float sc = gr[t] * rsqrtf(vr[t] + 1e-5f);
        par[PRSH + t] = br[t] - mr[t] * sc;
    }
    if (t < 64) {
        float s2 = g2[t] * rsqrtf(v2[t] + 1e-5f);
        float sm = gm[t] * rsqrtf(vm[t] + 1e-5f);
        par[PSHC + t] = (b2[t] - m2[t] * s2) + (betam[t] + (bmap[t] - mm[t]) * sm);
        par[PSMV + t] = sm;
        float s1 = g1[t] * rsqrtf(v1[t] + 1e-5f);
        par[PSC1 + t] = s1;
        par[PSH1 + t] = b1[t] - m1[t] * s1;
    }
}

__global__ __launch_bounds__(256, 4) void k1_conv1_gelu_reduce(
    const float* __restrict__ x, const float* __restrict__ par,
    unsigned* __restrict__ x1pad, float* __restrict__ rbuf)
{
    __shared__ float g_lds[COUT][65];

    int lane  = threadIdx.x & 63;
    int chunk = __builtin_amdgcn_readfirstlane(threadIdx.x >> 6);  // == group
    int b     = blockIdx.x >> 8;
    int p     = ((blockIdx.x & 255) << 6) + lane;
    int h = p >> 7, w = p & 127;

    float acc[16];
#pragma unroll
    for (int o = 0; o < 16; ++o) acc[o] = 0.f;
#pragma unroll 8
    for (int c = 0; c < CIN; ++c) {
        float xc = x[(b * CIN + c) * HW + p];
        const float* wrow = par + PW1T + c * 64 + chunk * 16;
#pragma unroll
        for (int o = 0; o < 16; ++o) acc[o] += xc * wrow[o];
    }

    unsigned pk[8];
#pragma unroll
    for (int o = 0; o < 16; ++o) {
        acc[o] = gelu_f(acc[o]);
        g_lds[chunk * 16 + o][lane] = acc[o];
    }
#pragma unroll
    for (int d = 0; d < 8; ++d) pk[d] = pack_bf2(acc[2 * d], acc[2 * d + 1]);
    unsigned* xo = x1pad + ((size_t)((b * GG + chunk) * PW + (h + 3)) * PW + (w + 3)) * 8;
    *(uint4*)xo       = make_uint4(pk[0], pk[1], pk[2], pk[3]);
    *(uint4*)(xo + 4) = make_uint4(pk[4], pk[5], pk[6], pk[7]);

    __syncthreads();

    float ra[4] = {0.f, 0.f, 0.f, 0.f};
#pragma unroll 8
    for (int c = 0; c < COUT; ++c) {
        float gv = g_lds[c][lane];
        const float* wrow = par + PWRT + c * 16 + chunk * 4;
#pragma unroll
        for (int jj = 0; jj < 4; ++jj) ra[jj] += gv * wrow[jj];
    }
    float t[4];
#pragma unroll
    for (int jj = 0; jj < 4; ++jj)
        t[jj] = fmaxf(ra[jj] + par[PRSH + chunk * 4 + jj], 0.f);
    *(float4*)&rbuf[((size_t)b * HW + p) * 16 + chunk * 4] =
        make_float4(t[0], t[1], t[2], t[3]);
}

// K23: per (b,g) block of 256 px. RUNTIME tap loops (#pragma unroll 1):
// rounds 9/10 proved that a fully-unrolled branch-free 49-tap body lets
// the pre-RA scheduler hoist ~400 VGPRs of loads -> scratch spill -> 2 GB
// HBM traffic. A real loop makes cross-iteration hoisting impossible
// (loop-carried acc dependency); live set ~45 VGPRs.
__global__ __launch_bounds__(256, 4) void k23_involution(
    const unsigned* __restrict__ x1pad, const float* __restrict__ rbuf,
    const float* __restrict__ wsp, const float* __restrict__ bsp,
    const float* __restrict__ par, unsigned* __restrict__ x2b)
{
    int bg = blockIdx.x >> 6;
    int g = bg & 3, b = bg >> 2;
    int p = ((blockIdx.x & 63) << 8) + threadIdx.x;
    int h = p >> 7, w0 = p & 127;

    float r[RED];
    {
        const float4* rp = (const float4*)&rbuf[((size_t)b * HW + p) * 16];
        float4 r0 = rp[0], r1 = rp[1], r2 = rp[2], r3 = rp[3];
        r[0]=r0.x; r[1]=r0.y; r[2]=r0.z; r[3]=r0.w;
        r[4]=r1.x; r[5]=r1.y; r[6]=r1.z; r[7]=r1.w;
        r[8]=r2.x; r[9]=r2.y; r[10]=r2.z; r[11]=r2.w;
        r[12]=r3.x; r[13]=r3.y; r[14]=r3.z; r[15]=r3.w;
    }

    const float* wrow = wsp + g * KKN * RED;
    const float* brow = bsp + g * KKN;
    const unsigned* base = x1pad + ((size_t)(bg * PW + h) * PW + w0) * 8;

    float acc[RED];
#pragma unroll
    for (int c = 0; c < RED; ++c) acc[c] = 0.f;

#pragma unroll 1
    for (int i = 0; i < 7; ++i) {
#pragma unroll 1
        for (int j = 0; j < 7; ++j) {
            int k = i * 7 + j;
            // generate this tap's dynamic weight (uniform s_load of ws row)
            const float* wk_row = wrow + k * RED;
            float s = brow[k];
#pragma unroll
            for (int jj = 0; jj < RED; ++jj) s += r[jj] * wk_row[jj];
            // apply it (unconditional — zero halo)
            const unsigned* tp = base + (size_t)(i * PW + j) * 8;
            uint4 A = *(const uint4*)tp;
            uint4 B = *(const uint4*)(tp + 4);
            float lo, hi;
            unpack_bf2(A.x, lo, hi); acc[0] += s*lo; acc[1] += s*hi;
            unpack_bf2(A.y, lo, hi); acc[2] += s*lo; acc[3] += s*hi;
            unpack_bf2(A.z, lo, hi); acc[4] += s*lo; acc[5] += s*hi;
            unpack_bf2(A.w, lo, hi); acc[6] += s*lo; acc[7] += s*hi;
            unpack_bf2(B.x, lo, hi); acc[8] += s*lo; acc[9] += s*hi;
            unpack_bf2(B.y, lo, hi); acc[10]+= s*lo; acc[11]+= s*hi;
            unpack_bf2(B.z, lo, hi); acc[12]+= s*lo; acc[13]+= s*hi;
            unpack_bf2(B.w, lo, hi); acc[14]+= s*lo; acc[15]+= s*hi;
        }
    }

    unsigned pk[8];
#pragma unroll
    for (int d = 0; d < 8; ++d) {
        int ch0 = g * RED + 2 * d, ch1 = ch0 + 1;
        float v0 = gelu_f(par[PSC1 + ch0] * acc[2 * d]     + par[PSH1 + ch0]);
        float v1 = gelu_f(par[PSC1 + ch1] * acc[2 * d + 1] + par[PSH1 + ch1]);
        pk[d] = pack_bf2(v0, v1);
    }
    unsigned* xo = x2b + ((size_t)bg * HW + p) * 8;
    *(uint4*)xo       = make_uint4(pk[0], pk[1], pk[2], pk[3]);
    *(uint4*)(xo + 4) = make_uint4(pk[4], pk[5], pk[6], pk[7]);
}

__global__ __launch_bounds__(256, 4) void k4_final(
    const unsigned* __restrict__ x2b, const float* __restrict__ x,
    const float* __restrict__ par, float* __restrict__ out)
{
    int lane  = threadIdx.x & 63;
    int chunk = __builtin_amdgcn_readfirstlane(threadIdx.x >> 6);
    int b     = blockIdx.x >> 8;
    int p     = ((blockIdx.x & 255) << 6) + lane;

    float acc[16];
#pragma unroll
    for (int o = 0; o < 16; ++o) acc[o] = 0.f;

#pragma unroll
    for (int gg = 0; gg < GG; ++gg) {
        const unsigned* up = x2b + ((size_t)(b * GG + gg) * HW + p) * 8;
        uint4 A = *(const uint4*)up;
        uint4 B = *(const uint4*)(up + 4);
        unsigned ud[8] = {A.x, A.y, A.z, A.w, B.x, B.y, B.z, B.w};
#pragma unroll
        for (int d = 0; d < 8; ++d) {
            float lo, hi;
            unpack_bf2(ud[d], lo, hi);
            int c0 = gg * 16 + 2 * d;
            const float* wr0 = par + PW2T + c0 * 64 + chunk * 16;
            const float* wr1 = wr0 + 64;
#pragma unroll
            for (int o = 0; o < 16; ++o) acc[o] += lo * wr0[o];
#pragma unroll
            for (int o = 0; o < 16; ++o) acc[o] += hi * wr1[o];
        }
    }
#pragma unroll 8
    for (int c = 0; c < CIN; ++c) {
        float xc = x[(b * CIN + c) * HW + p];
        const float* wrow = par + PWMT + c * 64 + chunk * 16;
#pragma unroll
        for (int o = 0; o < 16; ++o) acc[o] += xc * wrow[o];
    }
#pragma unroll
    for (int o = 0; o < 16; ++o) {
        int O = chunk * 16 + o;
        out[(size_t)(b * COUT + O) * HW + p] =
            gelu_f(par[PSMV + O] * acc[o] + par[PSHC + O]);
    }
}

extern "C" void kernel_launch(void* const* d_in, const int* in_sizes, int n_in,
                              void* d_out, int out_size, void* d_ws, size_t ws_size,
                              hipStream_t stream) {
    const float* x    = (const float*)d_in[0];
    const float* w1   = (const float*)d_in[1];
    const float* wr   = (const float*)d_in[2];
    const float* gr   = (const float*)d_in[3];
    const float* br   = (const float*)d_in[4];
    const float* mr   = (const float*)d_in[5];
    const float* vr   = (const float*)d_in[6];
    const float* wsp  = (const float*)d_in[7];
    const float* bsp  = (const float*)d_in[8];
    const float* g1   = (const float*)d_in[9];
    const float* b1   = (const float*)d_in[10];
    const float* m1   = (const float*)d_in[11];
    const float* v1   = (const float*)d_in[12];
    const float* w2   = (const float*)d_in[13];
    const float* g2   = (const float*)d_in[14];
    const float* b2   = (const float*)d_in[15];
    const float* m2   = (const float*)d_in[16];
    const float* v2   = (const float*)d_in[17];
    const float* wm   = (const float*)d_in[18];
    const float* bmap = (const float*)d_in[19];
    const float* gm   = (const float*)d_in[20];
    const float* betam= (const float*)d_in[21];
    const float* mm   = (const float*)d_in[22];
    const float* vm   = (const float*)d_in[23];

    unsigned* x1pad = (unsigned*)d_ws;
    float*    rbuf  = (float*)((char*)d_ws + OFF_RBUF);
    unsigned* x2b   = (unsigned*)((char*)d_ws + OFF_X2B);
    float*    par   = (float*)((char*)d_ws + OFF_PAR);

    int n16 = (16 * PPLANE * 32) / 16;
    k0_zero<<<(n16 + 255) / 256, 256, 0, stream>>>((uint4*)x1pad, n16);
    k0_prep<<<1, 256, 0, stream>>>(w1, wr, gr, br, mr, vr, g1, b1, m1, v1,
                                   w2, g2, b2, m2, v2, wm, bmap, gm, betam,
                                   mm, vm, par);
    k1_conv1_gelu_reduce<<<Bsz * HW / 64, 256, 0, stream>>>(x, par, x1pad, rbuf);
    k23_involution<<<Bsz * GG * HW / 256, 256, 0, stream>>>(
        x1pad, rbuf, wsp, bsp, par, x2b);
    k4_final<<<Bsz * HW / 64, 256, 0, stream>>>(x2b, x, par, (float*)d_out);
}